// Round 2
// baseline (1620.976 us; speedup 1.0000x reference)
//
#include <hip/hip_runtime.h>
#include <math.h>

// Problem constants
#define BATCH 4
#define SEQ   2048
#define HDIM  128
#define NHEAD 8
#define MROWS (BATCH*SEQ)    // 8192
#define QKVN  (3*NHEAD*HDIM) // 3072
#define YN    (NHEAD*HDIM)   // 1024

// ---------------------------------------------------------------------------
// Generic tiled fp32 GEMM: C[M,N] = A[M,K] @ B[K,N]
// 64x64 block tile, K-tiles of 64, 256 threads, 4x4 per thread.
// Requires M%64==0, N%64==0, K%64==0 (true for all our shapes).
// ---------------------------------------------------------------------------
__global__ __launch_bounds__(256) void gemm_tiled(
    const float* __restrict__ A, const float* __restrict__ B,
    float* __restrict__ C, int M, int N, int K)
{
    __shared__ float As[64][68];
    __shared__ float Bs[64][68];
    const int m0 = blockIdx.x * 64;
    const int n0 = blockIdx.y * 64;
    const int t  = threadIdx.x;
    const int tm = (t >> 4) << 2;   // 0..60
    const int tn = (t & 15) << 2;   // 0..60

    float acc[4][4] = {};

    for (int kt = 0; kt < K; kt += 64) {
        // cooperative loads: 64x64 = 1024 float4
        for (int i = t; i < 1024; i += 256) {
            int r = i >> 4, c4 = (i & 15) << 2;
            *(float4*)&As[r][c4] = *(const float4*)(A + (size_t)(m0 + r) * K + kt + c4);
            *(float4*)&Bs[r][c4] = *(const float4*)(B + (size_t)(kt + r) * N + n0 + c4);
        }
        __syncthreads();
        #pragma unroll 4
        for (int k = 0; k < 64; k += 4) {
            float av[4][4], bv[4][4];
            #pragma unroll
            for (int i = 0; i < 4; ++i) *(float4*)av[i] = *(const float4*)&As[tm + i][k];
            #pragma unroll
            for (int kk = 0; kk < 4; ++kk) *(float4*)bv[kk] = *(const float4*)&Bs[k + kk][tn];
            #pragma unroll
            for (int i = 0; i < 4; ++i)
                #pragma unroll
                for (int kk = 0; kk < 4; ++kk)
                    #pragma unroll
                    for (int j = 0; j < 4; ++j)
                        acc[i][j] += av[i][kk] * bv[kk][j];
        }
        __syncthreads();
    }
    #pragma unroll
    for (int i = 0; i < 4; ++i)
        *(float4*)(C + (size_t)(m0 + tm + i) * N + n0 + tn) = *(float4*)acc[i];
}

// ---------------------------------------------------------------------------
// Flash attention over the permuted-head layout.
// Head n's seq-row s2 lives at
//   XQKV[b][n*256 + (s2>>3)][(s2&7)*128 + h]   (+1024 for K, +2048 for V)
// Causal mask in s2-space. Output scattered into Y[8192][1024] likewise.
// BQ = BK = 32. 256 threads: t = (tq:4b, tk:4b).
// Each thread: 2 q-rows x 2 k-cols of S; 2 q-rows x 8 dims of O.
// ---------------------------------------------------------------------------
__global__ __launch_bounds__(256) void attn_fwd(
    const float* __restrict__ XQKV, float* __restrict__ Y)
{
    __shared__ float Qs[32][132];
    __shared__ float Ks[32][132];
    __shared__ float Vs[32][132];
    __shared__ float Ps[32][36];

    const int qt = blockIdx.x;   // 0..63
    const int n  = blockIdx.y;   // 0..7
    const int b  = blockIdx.z;   // 0..3
    const int t  = threadIdx.x;
    const int tq = t >> 4;       // 0..15 (owns rows 2tq, 2tq+1)
    const int tk = t & 15;       // 0..15

    const float* Xb = XQKV + (size_t)b * SEQ * QKVN;
    const int baserow = n * 256;
    const int q0 = qt * 32;
    const float scale = 0.08838834764831845f; // 1/sqrt(128)
    const float NEG = -3.0e38f;

    // Load Q tile (32 rows x 128) : 1024 float4
    for (int i = t; i < 1024; i += 256) {
        int r = i >> 5, c4 = (i & 31) << 2;
        int s2 = q0 + r;
        *(float4*)&Qs[r][c4] =
            *(const float4*)(Xb + (size_t)(baserow + (s2 >> 3)) * QKVN + (s2 & 7) * 128 + c4);
    }

    float mrow[2] = {NEG, NEG};
    float lrow[2] = {0.f, 0.f};
    float acc[2][8] = {};

    const int nkt = qt + 1;  // causal: K-tiles 0..qt
    for (int kt = 0; kt < nkt; ++kt) {
        const int k0 = kt * 32;
        __syncthreads();  // protect Ks/Vs (prev PV) and Qs (first-iter load)
        for (int i = t; i < 1024; i += 256) {
            int r = i >> 5, c4 = (i & 31) << 2;
            int s2 = k0 + r;
            const float* base = Xb + (size_t)(baserow + (s2 >> 3)) * QKVN + (s2 & 7) * 128;
            *(float4*)&Ks[r][c4] = *(const float4*)(base + 1024 + c4);
            *(float4*)&Vs[r][c4] = *(const float4*)(base + 2048 + c4);
        }
        __syncthreads();

        // S = Q K^T for rows 2tq+i, cols 2tk+j
        float s[2][2] = {};
        #pragma unroll 8
        for (int d = 0; d < 128; d += 4) {
            float qv[2][4], kv[2][4];
            *(float4*)qv[0] = *(const float4*)&Qs[2 * tq + 0][d];
            *(float4*)qv[1] = *(const float4*)&Qs[2 * tq + 1][d];
            *(float4*)kv[0] = *(const float4*)&Ks[2 * tk + 0][d];
            *(float4*)kv[1] = *(const float4*)&Ks[2 * tk + 1][d];
            #pragma unroll
            for (int i = 0; i < 2; ++i)
                #pragma unroll
                for (int j = 0; j < 2; ++j)
                    #pragma unroll
                    for (int dd = 0; dd < 4; ++dd)
                        s[i][j] += qv[i][dd] * kv[j][dd];
        }
        // scale + causal mask (only bites when kt == qt)
        #pragma unroll
        for (int i = 0; i < 2; ++i)
            #pragma unroll
            for (int j = 0; j < 2; ++j) {
                s[i][j] *= scale;
                if (k0 + 2 * tk + j > q0 + 2 * tq + i) s[i][j] = NEG;
            }

        // online softmax update (reduce across the 16 tk lanes; xor 1/2/4/8
        // stays inside the 16-lane group of the 64-lane wave)
        float p[2][2];
        #pragma unroll
        for (int i = 0; i < 2; ++i) {
            float rm = fmaxf(s[i][0], s[i][1]);
            rm = fmaxf(rm, __shfl_xor(rm, 1));
            rm = fmaxf(rm, __shfl_xor(rm, 2));
            rm = fmaxf(rm, __shfl_xor(rm, 4));
            rm = fmaxf(rm, __shfl_xor(rm, 8));
            float nm = fmaxf(mrow[i], rm);
            float alpha = __expf(mrow[i] - nm);
            p[i][0] = __expf(s[i][0] - nm);
            p[i][1] = __expf(s[i][1] - nm);
            float rs = p[i][0] + p[i][1];
            rs += __shfl_xor(rs, 1);
            rs += __shfl_xor(rs, 2);
            rs += __shfl_xor(rs, 4);
            rs += __shfl_xor(rs, 8);
            lrow[i] = lrow[i] * alpha + rs;
            mrow[i] = nm;
            #pragma unroll
            for (int dd = 0; dd < 8; ++dd) acc[i][dd] *= alpha;
        }
        // stage P
        Ps[2 * tq + 0][2 * tk + 0] = p[0][0];
        Ps[2 * tq + 0][2 * tk + 1] = p[0][1];
        Ps[2 * tq + 1][2 * tk + 0] = p[1][0];
        Ps[2 * tq + 1][2 * tk + 1] = p[1][1];
        __syncthreads();

        // PV: O[2tq+i][tk*8 + dd] += sum_k P[2tq+i][k] * V[k][tk*8+dd]
        #pragma unroll 4
        for (int k = 0; k < 32; ++k) {
            float4 v0 = *(const float4*)&Vs[k][tk * 8];
            float4 v1 = *(const float4*)&Vs[k][tk * 8 + 4];
            float p0 = Ps[2 * tq + 0][k];
            float p1 = Ps[2 * tq + 1][k];
            acc[0][0] += p0 * v0.x; acc[0][1] += p0 * v0.y;
            acc[0][2] += p0 * v0.z; acc[0][3] += p0 * v0.w;
            acc[0][4] += p0 * v1.x; acc[0][5] += p0 * v1.y;
            acc[0][6] += p0 * v1.z; acc[0][7] += p0 * v1.w;
            acc[1][0] += p1 * v0.x; acc[1][1] += p1 * v0.y;
            acc[1][2] += p1 * v0.z; acc[1][3] += p1 * v0.w;
            acc[1][4] += p1 * v1.x; acc[1][5] += p1 * v1.y;
            acc[1][6] += p1 * v1.z; acc[1][7] += p1 * v1.w;
        }
    }

    // epilogue: normalize and scatter into Y[8192][1024]
    #pragma unroll
    for (int i = 0; i < 2; ++i) {
        float inv = 1.0f / lrow[i];
        int s2 = q0 + 2 * tq + i;
        size_t row = (size_t)b * SEQ + baserow + (s2 >> 3);
        float* dst = Y + row * YN + (s2 & 7) * 128 + tk * 8;
        float4 o0, o1;
        o0.x = acc[i][0] * inv; o0.y = acc[i][1] * inv;
        o0.z = acc[i][2] * inv; o0.w = acc[i][3] * inv;
        o1.x = acc[i][4] * inv; o1.y = acc[i][5] * inv;
        o1.z = acc[i][6] * inv; o1.w = acc[i][7] * inv;
        *(float4*)dst = o0;
        *(float4*)(dst + 4) = o1;
    }
}

// ---------------------------------------------------------------------------
extern "C" void kernel_launch(void* const* d_in, const int* in_sizes, int n_in,
                              void* d_out, int out_size, void* d_ws, size_t ws_size,
                              hipStream_t stream)
{
    const float* x    = (const float*)d_in[0];  // [4,2048,128]
    const float* qkv  = (const float*)d_in[1];  // [128,3072]
    const float* proj = (const float*)d_in[2];  // [1024,128]
    float* out = (float*)d_out;                 // [8192,128]

    float* XQKV = (float*)d_ws;                 // 8192*3072 floats = 96 MB
    float* Yb   = XQKV + (size_t)MROWS * QKVN;  // 8192*1024 floats = 32 MB

    // 1) XQKV = x @ qkv
    gemm_tiled<<<dim3(MROWS / 64, QKVN / 64), 256, 0, stream>>>(
        x, qkv, XQKV, MROWS, QKVN, HDIM);

    // 2) flash attention (permuted-head layout), Y = attention output gathered
    attn_fwd<<<dim3(SEQ / 32, NHEAD, BATCH), 256, 0, stream>>>(XQKV, Yb);

    // 3) out = Y @ projection
    gemm_tiled<<<dim3(MROWS / 64, HDIM / 64), 256, 0, stream>>>(
        Yb, proj, out, MROWS, HDIM, YN);
}

// Round 3
// 338.046 us; speedup vs baseline: 4.7951x; 4.7951x over previous
//
#include <hip/hip_runtime.h>
#include <math.h>

// Problem constants
#define BATCH 4
#define SEQ   2048
#define HDIM  128
#define NHEAD 8
#define MROWS (BATCH*SEQ)    // 8192
#define QKVN  (3*NHEAD*HDIM) // 3072
#define YN    (NHEAD*HDIM)   // 1024

#define CE 0.08838834764831845f   // 1/sqrt(128)

using bfrag = __attribute__((ext_vector_type(8))) short;  // 8 bf16 (4 VGPRs)
using f32x4 = __attribute__((ext_vector_type(4))) float;
using s16x4 = __attribute__((ext_vector_type(4))) short;

__device__ __forceinline__ f32x4 mfma16(bfrag a, bfrag b, f32x4 c) {
    return __builtin_amdgcn_mfma_f32_16x16x32_bf16(a, b, c, 0, 0, 0);
}
__device__ __forceinline__ short f2bf(float f) {
    union { float f; unsigned u; } v; v.f = f;
    unsigned r = v.u + 0x7FFFu + ((v.u >> 16) & 1u);  // round-to-nearest-even
    return (short)(r >> 16);
}
__device__ __forceinline__ f32x4 z4() { f32x4 z; z[0]=0.f; z[1]=0.f; z[2]=0.f; z[3]=0.f; return z; }

// ---------------------------------------------------------------------------
// Converters
// ---------------------------------------------------------------------------
__global__ __launch_bounds__(256) void conv_x(const float* __restrict__ x, short* __restrict__ XB) {
    int i = (blockIdx.x * 256 + threadIdx.x) * 4;   // 8192*128 = 1048576 elems
    float4 v = *(const float4*)(x + i);
    s16x4 o; o[0] = f2bf(v.x); o[1] = f2bf(v.y); o[2] = f2bf(v.z); o[3] = f2bf(v.w);
    *(s16x4*)(XB + i) = o;
}
__global__ __launch_bounds__(256) void conv_qkvT(const float* __restrict__ q, short* __restrict__ qT) {
    int t = blockIdx.x * 256 + threadIdx.x;         // 3072*128 = 393216
    int n = t >> 7, k = t & 127;
    qT[t] = f2bf(q[(size_t)k * QKVN + n]);          // qT[n][k] = qkv[k][n]
}
__global__ __launch_bounds__(256) void conv_projT(const float* __restrict__ p, short* __restrict__ pT) {
    int t = blockIdx.x * 256 + threadIdx.x;         // 128*1024 = 131072
    int h = t >> 10, r = t & 1023;
    pT[t] = f2bf(p[(size_t)r * HDIM + h]);          // pT[h][r] = proj[r][h]
}

// ---------------------------------------------------------------------------
// GEMM1: XQKV[8192][3072] (bf16) = XB[8192][128] @ qkv ; B given as qkvT[n][k].
// Grid (64, 24), 256 thr = 4 waves, wave tile 64x64, K = 4 chunks of 32.
// All operand reads straight from global (L2-resident), no LDS.
// ---------------------------------------------------------------------------
__global__ __launch_bounds__(256) void gemm_qkv(
    const short* __restrict__ XB, const short* __restrict__ qkvT, short* __restrict__ XQKV)
{
    const int t = threadIdx.x, lane = t & 63, w = t >> 6;
    const int lr = lane & 15, lg = lane >> 4;
    const int m0 = blockIdx.x * 128 + (w >> 1) * 64;
    const int n0 = blockIdx.y * 128 + (w & 1) * 64;

    f32x4 acc[4][4];
    #pragma unroll
    for (int i = 0; i < 4; ++i)
        #pragma unroll
        for (int j = 0; j < 4; ++j) acc[i][j] = z4();

    #pragma unroll
    for (int c = 0; c < 4; ++c) {
        bfrag a[4], bb[4];
        #pragma unroll
        for (int rt = 0; rt < 4; ++rt)
            a[rt] = *(const bfrag*)(XB + (size_t)(m0 + rt * 16 + lr) * 128 + c * 32 + lg * 8);
        #pragma unroll
        for (int nt = 0; nt < 4; ++nt)
            bb[nt] = *(const bfrag*)(qkvT + (size_t)(n0 + nt * 16 + lr) * 128 + c * 32 + lg * 8);
        #pragma unroll
        for (int rt = 0; rt < 4; ++rt)
            #pragma unroll
            for (int nt = 0; nt < 4; ++nt)
                acc[rt][nt] = mfma16(a[rt], bb[nt], acc[rt][nt]);
    }
    #pragma unroll
    for (int rt = 0; rt < 4; ++rt)
        #pragma unroll
        for (int nt = 0; nt < 4; ++nt)
            #pragma unroll
            for (int j = 0; j < 4; ++j)
                XQKV[(size_t)(m0 + rt * 16 + lg * 4 + j) * QKVN + n0 + nt * 16 + lr] =
                    f2bf(acc[rt][nt][j]);
}

// ---------------------------------------------------------------------------
// MFMA flash attention over the permuted-head layout.
// Head n's seq-row s2: XQKV[b][n*256 + (s2>>3)][(s2&7)*128 + h] (+1024 K, +2048 V).
// Block: 256 thr = 4 waves; wave owns 32 q-rows (2 row-tiles of 16); QBLK=128.
// KVBLK=32 per step. Q in regs; K row-major LDS; V transposed LDS; P per-wave LDS.
// Row-sum via P*ones MFMA; T13 defer-rescale; XCD swizzle on blockIdx.
// ---------------------------------------------------------------------------
__global__ __launch_bounds__(256) void attn_mfma(
    const short* __restrict__ X, short* __restrict__ Y)
{
    __shared__ short Ks[32][136];    // stride 272B = 17*16B (b128-aligned rows)
    __shared__ short Vt[128][36];    // stride 72B (b64-aligned), odd-dword spread
    __shared__ short Ps[4][32][40];  // per-wave P, stride 80B (b128-aligned)

    const int t = threadIdx.x, lane = t & 63, w = t >> 6;
    const int lr = lane & 15, lg = lane >> 4;

    int flat = blockIdx.x;                       // 512 blocks, 512%8==0
    flat = (flat & 7) * 64 + (flat >> 3);        // XCD swizzle: same head -> same XCD
    const int qt = flat & 15;
    const int n  = (flat >> 4) & 7;
    const int b  = flat >> 7;

    const int q0 = qt * 128 + w * 32;            // this wave's first q row
    const size_t Xb = (size_t)b * SEQ * QKVN;
    const int hb = n * 256;

    // Q fragments in registers: 2 row-tiles x 4 K-chunks
    bfrag qf[2][4];
    #pragma unroll
    for (int rt = 0; rt < 2; ++rt) {
        int s2 = q0 + rt * 16 + lr;
        const short* qp = X + Xb + (size_t)(hb + (s2 >> 3)) * QKVN + (s2 & 7) * 128 + lg * 8;
        #pragma unroll
        for (int c = 0; c < 4; ++c) qf[rt][c] = *(const bfrag*)(qp + c * 32);
    }

    float mrow[2][4], lrow[2][4];
    f32x4 o[2][8];
    #pragma unroll
    for (int rt = 0; rt < 2; ++rt) {
        #pragma unroll
        for (int j = 0; j < 4; ++j) { mrow[rt][j] = -3.0e38f; lrow[rt][j] = 0.f; }
        #pragma unroll
        for (int dt = 0; dt < 8; ++dt) o[rt][dt] = z4();
    }

    const int nst = qt * 4 + 4;   // causal: kv steps cover [0, qt*128+128)
    for (int s = 0; s < nst; ++s) {
        const int k0 = s * 32;
        __syncthreads();
        // ---- stage K tile: 32 rows x 128, thread = (row t>>3, 16-elem chunk t&7)
        {
            int s2 = k0 + (t >> 3);
            const short* src = X + Xb + (size_t)(hb + (s2 >> 3)) * QKVN + 1024 + (s2 & 7) * 128 + (t & 7) * 16;
            *(int4*)&Ks[t >> 3][(t & 7) * 16]     = *(const int4*)src;
            *(int4*)&Ks[t >> 3][(t & 7) * 16 + 8] = *(const int4*)(src + 8);
        }
        // ---- stage V transposed: Vt[d][kv]; thread: d in {t&63, (t&63)+64}, kv quad
        {
            int dl = t & 63, kq = (t >> 6) * 4;
            #pragma unroll
            for (int p = 0; p < 2; ++p) {
                int kv0 = kq + p * 16;
                #pragma unroll
                for (int dd = 0; dd < 2; ++dd) {
                    int d = dl + dd * 64;
                    s16x4 pk;
                    #pragma unroll
                    for (int j = 0; j < 4; ++j) {
                        int s2 = k0 + kv0 + j;
                        pk[j] = X[Xb + (size_t)(hb + (s2 >> 3)) * QKVN + 2048 + (s2 & 7) * 128 + d];
                    }
                    *(s16x4*)&Vt[d][kv0] = pk;
                }
            }
        }
        __syncthreads();

        // ---- QK^T: S[32 rows][32 cols] per wave
        bfrag kb[2][4];
        #pragma unroll
        for (int kt = 0; kt < 2; ++kt)
            #pragma unroll
            for (int c = 0; c < 4; ++c)
                kb[kt][c] = *(const bfrag*)&Ks[kt * 16 + lr][c * 32 + lg * 8];
        f32x4 sA[2][2];
        #pragma unroll
        for (int rt = 0; rt < 2; ++rt)
            #pragma unroll
            for (int kt = 0; kt < 2; ++kt) sA[rt][kt] = z4();
        #pragma unroll
        for (int rt = 0; rt < 2; ++rt)
            #pragma unroll
            for (int kt = 0; kt < 2; ++kt)
                #pragma unroll
                for (int c = 0; c < 4; ++c)
                    sA[rt][kt] = mfma16(qf[rt][c], kb[kt][c], sA[rt][kt]);

        // ---- causal mask + row max (16-lane shuffle reduce)
        float pmax[2][4];
        bool need = false;
        #pragma unroll
        for (int rt = 0; rt < 2; ++rt)
            #pragma unroll
            for (int j = 0; j < 4; ++j) {
                int rg = q0 + rt * 16 + lg * 4 + j;
                float v0 = sA[rt][0][j], v1 = sA[rt][1][j];
                if (k0 + lr > rg)      v0 = -3.0e38f;
                if (k0 + 16 + lr > rg) v1 = -3.0e38f;
                sA[rt][0][j] = v0; sA[rt][1][j] = v1;
                float mx = fmaxf(v0, v1);
                mx = fmaxf(mx, __shfl_xor(mx, 1));
                mx = fmaxf(mx, __shfl_xor(mx, 2));
                mx = fmaxf(mx, __shfl_xor(mx, 4));
                mx = fmaxf(mx, __shfl_xor(mx, 8));
                pmax[rt][j] = mx;
                need = need || (mx > mrow[rt][j] + 90.0f);   // T13: THR = 8/scale
            }
        if (__any(need ? 1 : 0)) {
            #pragma unroll
            for (int rt = 0; rt < 2; ++rt)
                #pragma unroll
                for (int j = 0; j < 4; ++j) {
                    float nm = fmaxf(mrow[rt][j], pmax[rt][j]);
                    float al = __expf((mrow[rt][j] - nm) * CE);
                    mrow[rt][j] = nm;
                    lrow[rt][j] *= al;
                    #pragma unroll
                    for (int dt = 0; dt < 8; ++dt) o[rt][dt][j] *= al;
                }
        }

        // ---- P = exp((S - m)*scale), staged bf16 per-wave (no barrier needed)
        #pragma unroll
        for (int rt = 0; rt < 2; ++rt)
            #pragma unroll
            for (int j = 0; j < 4; ++j) {
                float m = mrow[rt][j];
                int qr = rt * 16 + lg * 4 + j;
                Ps[w][qr][lr]      = f2bf(__expf((sA[rt][0][j] - m) * CE));
                Ps[w][qr][16 + lr] = f2bf(__expf((sA[rt][1][j] - m) * CE));
            }

        // ---- P A-frags; l via P*ones MFMA; PV
        bfrag pa[2];
        #pragma unroll
        for (int rt = 0; rt < 2; ++rt)
            pa[rt] = *(const bfrag*)&Ps[w][rt * 16 + lr][lg * 8];
        bfrag ones;
        #pragma unroll
        for (int i = 0; i < 8; ++i) ones[i] = (short)0x3F80;  // bf16 1.0
        #pragma unroll
        for (int rt = 0; rt < 2; ++rt) {
            f32x4 ls = mfma16(pa[rt], ones, z4());
            #pragma unroll
            for (int j = 0; j < 4; ++j) lrow[rt][j] += ls[j];
        }
        #pragma unroll
        for (int dt = 0; dt < 8; ++dt) {
            s16x4 u0 = *(const s16x4*)&Vt[dt * 16 + lr][lg * 8];
            s16x4 u1 = *(const s16x4*)&Vt[dt * 16 + lr][lg * 8 + 4];
            bfrag vb;
            vb[0]=u0[0]; vb[1]=u0[1]; vb[2]=u0[2]; vb[3]=u0[3];
            vb[4]=u1[0]; vb[5]=u1[1]; vb[6]=u1[2]; vb[7]=u1[3];
            #pragma unroll
            for (int rt = 0; rt < 2; ++rt)
                o[rt][dt] = mfma16(pa[rt], vb, o[rt][dt]);
        }
    }

    // ---- epilogue: normalize, scatter bf16 into Y[8192][1024] (permuted rows)
    #pragma unroll
    for (int rt = 0; rt < 2; ++rt)
        #pragma unroll
        for (int j = 0; j < 4; ++j) {
            int s2 = q0 + rt * 16 + lg * 4 + j;
            size_t yrow = (size_t)b * SEQ + hb + (s2 >> 3);
            float inv = 1.0f / lrow[rt][j];
            short* yp = Y + yrow * YN + (s2 & 7) * 128 + lr;
            #pragma unroll
            for (int dt = 0; dt < 8; ++dt)
                yp[dt * 16] = f2bf(o[rt][dt][j] * inv);
        }
}

// ---------------------------------------------------------------------------
// GEMM2: out[8192][128] (f32) = Y[8192][1024](bf16) @ proj ; B as projT[h][k].
// Grid (64), 4 waves, wave tile 64x64 (block covers full N=128), K = 32 chunks.
// ---------------------------------------------------------------------------
__global__ __launch_bounds__(256) void gemm_out(
    const short* __restrict__ Yb, const short* __restrict__ projT, float* __restrict__ out)
{
    const int t = threadIdx.x, lane = t & 63, w = t >> 6;
    const int lr = lane & 15, lg = lane >> 4;
    const int m0 = blockIdx.x * 128 + (w >> 1) * 64;
    const int n0 = (w & 1) * 64;

    f32x4 acc[4][4];
    #pragma unroll
    for (int i = 0; i < 4; ++i)
        #pragma unroll
        for (int j = 0; j < 4; ++j) acc[i][j] = z4();

    for (int c = 0; c < 32; ++c) {
        bfrag a[4], bb[4];
        #pragma unroll
        for (int rt = 0; rt < 4; ++rt)
            a[rt] = *(const bfrag*)(Yb + (size_t)(m0 + rt * 16 + lr) * YN + c * 32 + lg * 8);
        #pragma unroll
        for (int nt = 0; nt < 4; ++nt)
            bb[nt] = *(const bfrag*)(projT + (size_t)(n0 + nt * 16 + lr) * YN + c * 32 + lg * 8);
        #pragma unroll
        for (int rt = 0; rt < 4; ++rt)
            #pragma unroll
            for (int nt = 0; nt < 4; ++nt)
                acc[rt][nt] = mfma16(a[rt], bb[nt], acc[rt][nt]);
    }
    #pragma unroll
    for (int rt = 0; rt < 4; ++rt)
        #pragma unroll
        for (int nt = 0; nt < 4; ++nt)
            #pragma unroll
            for (int j = 0; j < 4; ++j)
                out[(size_t)(m0 + rt * 16 + lg * 4 + j) * HDIM + n0 + nt * 16 + lr] =
                    acc[rt][nt][j];
}

// ---------------------------------------------------------------------------
extern "C" void kernel_launch(void* const* d_in, const int* in_sizes, int n_in,
                              void* d_out, int out_size, void* d_ws, size_t ws_size,
                              hipStream_t stream)
{
    const float* x    = (const float*)d_in[0];  // [4,2048,128]
    const float* qkv  = (const float*)d_in[1];  // [128,3072]
    const float* proj = (const float*)d_in[2];  // [1024,128]
    float* out = (float*)d_out;                 // [8192,128]

    short* XB    = (short*)d_ws;                          // 8192*128   bf16
    short* qkvT  = XB    + (size_t)MROWS * HDIM;          // 3072*128
    short* projT = qkvT  + (size_t)QKVN * HDIM;           // 128*1024
    short* XQKV  = projT + (size_t)HDIM * YN;             // 8192*3072
    short* Yb    = XQKV  + (size_t)MROWS * QKVN;          // 8192*1024
    // total ~70 MB of workspace

    conv_x    <<<MROWS * HDIM / 1024, 256, 0, stream>>>(x, XB);
    conv_qkvT <<<QKVN * HDIM / 256,  256, 0, stream>>>(qkv, qkvT);
    conv_projT<<<HDIM * YN / 256,    256, 0, stream>>>(proj, projT);

    gemm_qkv<<<dim3(MROWS / 128, QKVN / 128), 256, 0, stream>>>(XB, qkvT, XQKV);
    attn_mfma<<<(SEQ / 128) * NHEAD * BATCH, 256, 0, stream>>>(XQKV, Yb);
    gemm_out<<<MROWS / 128, 256, 0, stream>>>(Yb, projT, out);
}

// Round 5
// 337.909 us; speedup vs baseline: 4.7971x; 1.0004x over previous
//
#include <hip/hip_runtime.h>
#include <math.h>

// Problem constants
#define BATCH 4
#define SEQ   2048
#define HDIM  128
#define NHEAD 8
#define MROWS (BATCH*SEQ)    // 8192
#define QKVN  (3*NHEAD*HDIM) // 3072
#define YN    (NHEAD*HDIM)   // 1024

#define CS 0.12751744f   // (1/sqrt(128)) * log2(e)

using bfrag = __attribute__((ext_vector_type(8))) short;  // 8 bf16 (4 VGPRs)
using f32x4 = __attribute__((ext_vector_type(4))) float;
using s16x4 = __attribute__((ext_vector_type(4))) short;

__device__ __forceinline__ f32x4 mfma16(bfrag a, bfrag b, f32x4 c) {
    return __builtin_amdgcn_mfma_f32_16x16x32_bf16(a, b, c, 0, 0, 0);
}
__device__ __forceinline__ short f2bf(float f) {
    union { float f; unsigned u; } v; v.f = f;
    unsigned r = v.u + 0x7FFFu + ((v.u >> 16) & 1u);  // RNE
    return (short)(r >> 16);
}
__device__ __forceinline__ f32x4 z4() { f32x4 z; z[0]=0.f; z[1]=0.f; z[2]=0.f; z[3]=0.f; return z; }

// ---------------------------------------------------------------------------
// Converters
// ---------------------------------------------------------------------------
__global__ __launch_bounds__(256) void conv_x(const float* __restrict__ x, short* __restrict__ XB) {
    int i = (blockIdx.x * 256 + threadIdx.x) * 4;
    float4 v = *(const float4*)(x + i);
    s16x4 o; o[0] = f2bf(v.x); o[1] = f2bf(v.y); o[2] = f2bf(v.z); o[3] = f2bf(v.w);
    *(s16x4*)(XB + i) = o;
}
__global__ __launch_bounds__(256) void conv_qkvT(const float* __restrict__ q, short* __restrict__ qT) {
    int t = blockIdx.x * 256 + threadIdx.x;         // 3072*128
    int n = t >> 7, k = t & 127;
    qT[t] = f2bf(q[(size_t)k * QKVN + n]);          // qT[n][k] = qkv[k][n]
}
__global__ __launch_bounds__(256) void conv_projT(const float* __restrict__ p, short* __restrict__ pT) {
    int t = blockIdx.x * 256 + threadIdx.x;         // 128*1024
    int h = t >> 10, r = t & 1023;
    pT[t] = f2bf(p[(size_t)r * HDIM + h]);          // pT[h][r] = proj[r][h]
}

// ---------------------------------------------------------------------------
// GEMM1: computes x @ qkv and scatters Q/K/V into per-head layouts:
//   Qh/Kh/Vh[(b*8+n)*2048 + s2][h]   (bf16, contiguous per head; 8.4M elems each)
// Output col jj (within part) of global row r=b*2048+s maps to:
//   n = s>>8 ; s2 = (s&255)*8 + (jj>>7) ; h = jj&127
// Block tile 128x128 (4 waves, 64x64 each). blockIdx.y encodes part & c8.
// ---------------------------------------------------------------------------
__global__ __launch_bounds__(256) void gemm_qkv(
    const short* __restrict__ XB, const short* __restrict__ qkvT,
    short* __restrict__ Qh, short* __restrict__ Kh, short* __restrict__ Vh)
{
    const int t = threadIdx.x, lane = t & 63, w = t >> 6;
    const int lr = lane & 15, lg = lane >> 4;
    const int m0 = blockIdx.x * 128 + (w >> 1) * 64;
    const int n0 = blockIdx.y * 128 + (w & 1) * 64;

    f32x4 acc[4][4];
    #pragma unroll
    for (int i = 0; i < 4; ++i)
        #pragma unroll
        for (int j = 0; j < 4; ++j) acc[i][j] = z4();

    #pragma unroll
    for (int c = 0; c < 4; ++c) {
        bfrag a[4], bb[4];
        #pragma unroll
        for (int rt = 0; rt < 4; ++rt)
            a[rt] = *(const bfrag*)(XB + (size_t)(m0 + rt * 16 + lr) * 128 + c * 32 + lg * 8);
        #pragma unroll
        for (int nt = 0; nt < 4; ++nt)
            bb[nt] = *(const bfrag*)(qkvT + (size_t)(n0 + nt * 16 + lr) * 128 + c * 32 + lg * 8);
        #pragma unroll
        for (int rt = 0; rt < 4; ++rt)
            #pragma unroll
            for (int nt = 0; nt < 4; ++nt)
                acc[rt][nt] = mfma16(a[rt], bb[nt], acc[rt][nt]);
    }

    const int part = blockIdx.y >> 3, c8 = blockIdx.y & 7;
    short* dst = (part == 0) ? Qh : ((part == 1) ? Kh : Vh);
    #pragma unroll
    for (int rt = 0; rt < 4; ++rt)
        #pragma unroll
        for (int j = 0; j < 4; ++j) {
            int r = m0 + rt * 16 + lg * 4 + j;
            int b = r >> 11, sl = r & 2047;
            int n = sl >> 8, s2 = (sl & 255) * 8 + c8;
            size_t rowbase = ((size_t)((b * 8 + n) * 2048 + s2)) * 128;
            #pragma unroll
            for (int nt = 0; nt < 4; ++nt) {
                int h = (w & 1) * 64 + nt * 16 + lr;
                dst[rowbase + h] = f2bf(acc[rt][nt][j]);
            }
        }
}

// ---------------------------------------------------------------------------
// Transpose V per head: Vh[bn][s2][d] -> Vt[bn][d][s2]. 64x64 LDS tiles,
// coalesced on both sides.
// ---------------------------------------------------------------------------
__global__ __launch_bounds__(256) void transp_v(
    const short* __restrict__ Vh, short* __restrict__ Vt)
{
    __shared__ short Ls[64][72];
    const int bn = blockIdx.z, s20 = blockIdx.x * 64, d0 = blockIdx.y * 64;
    const int t = threadIdx.x;
    const short* src = Vh + ((size_t)bn * SEQ + s20) * 128 + d0;
    {
        int r = t >> 2, ch = (t & 3) * 16;
        *(int4*)&Ls[r][ch]     = *(const int4*)(src + (size_t)r * 128 + ch);
        *(int4*)&Ls[r][ch + 8] = *(const int4*)(src + (size_t)r * 128 + ch + 8);
    }
    __syncthreads();
    {
        int dr = t >> 2, ch = (t & 3) * 16;
        short tmp[16];
        #pragma unroll
        for (int i = 0; i < 16; ++i) tmp[i] = Ls[ch + i][dr];
        short* dp = Vt + ((size_t)bn * HDIM + d0 + dr) * SEQ + s20 + ch;
        *(int4*)dp       = *(int4*)&tmp[0];
        *(int4*)(dp + 8) = *(int4*)&tmp[8];
    }
}

// ---------------------------------------------------------------------------
// LDS-free flash attention. QBLK=64, KVBLK=64; block = 4 waves x 16 q-rows.
// Paired q-tiles (p, 31-p) -> every block does exactly 33 kv-steps.
// K/V fragments read straight from global (L1/L2-shared across waves).
// Only LDS: per-wave Ps (P C-layout -> A-layout), wave-fenced, no barriers.
// ---------------------------------------------------------------------------
__global__ __launch_bounds__(256) void attn2(
    const short* __restrict__ Qh, const short* __restrict__ Kh,
    const short* __restrict__ Vt, short* __restrict__ Y)
{
    __shared__ short Ps[4][16][72];

    const int t = threadIdx.x, lane = t & 63, w = t >> 6;
    const int lr = lane & 15, lg = lane >> 4;

    // bijective swizzle: 16 blocks of a (b,n) land on one XCD (g%8 = bn%8)
    const int g = blockIdx.x;                 // 0..511
    const int r8 = g & 7, q = g >> 3;
    const int bn = (q >> 4) * 8 + r8;         // 0..31
    const int p  = q & 15;                    // pair id
    const int b = bn >> 3, n = bn & 7;

    const short* Qb = Qh + (size_t)bn * SEQ * HDIM;
    const short* Kb = Kh + (size_t)bn * SEQ * HDIM;
    const short* Vb = Vt + (size_t)bn * HDIM * SEQ;

    bfrag ones;
    #pragma unroll
    for (int i = 0; i < 8; ++i) ones[i] = (short)0x3F80;   // bf16 1.0

    #pragma unroll 1
    for (int tile = 0; tile < 2; ++tile) {
        const int qt = tile ? (31 - p) : p;
        const int q0 = qt * 64 + w * 16;

        bfrag qf[4];
        #pragma unroll
        for (int c = 0; c < 4; ++c)
            qf[c] = *(const bfrag*)(Qb + (size_t)(q0 + lr) * 128 + c * 32 + lg * 8);

        float mcs[4], l[4];
        f32x4 o[8];
        #pragma unroll
        for (int j = 0; j < 4; ++j) { mcs[j] = -1.0e30f; l[j] = 0.f; }
        #pragma unroll
        for (int dt = 0; dt < 8; ++dt) o[dt] = z4();

        for (int s = 0; s <= qt; ++s) {
            const int k0 = s * 64;

            // ---- QK^T : S[16 rows][64 cols]
            f32x4 sA[4];
            #pragma unroll
            for (int kt = 0; kt < 4; ++kt) sA[kt] = z4();
            #pragma unroll
            for (int kt = 0; kt < 4; ++kt) {
                const short* kp = Kb + (size_t)(k0 + kt * 16 + lr) * 128 + lg * 8;
                #pragma unroll
                for (int c = 0; c < 4; ++c) {
                    bfrag kb = *(const bfrag*)(kp + c * 32);
                    sA[kt] = mfma16(qf[c], kb, sA[kt]);
                }
            }
            // causal mask (only final step of this q-tile can mask)
            if (s == qt) {
                #pragma unroll
                for (int kt = 0; kt < 4; ++kt)
                    #pragma unroll
                    for (int j = 0; j < 4; ++j)
                        if (k0 + kt * 16 + lr > q0 + lg * 4 + j)
                            sA[kt][j] = -3.0e38f;
            }

            // ---- row max (4 cols in-thread, then 16-lane lr reduce)
            float pm[4];
            bool need = false;
            #pragma unroll
            for (int j = 0; j < 4; ++j) {
                float mx = fmaxf(fmaxf(sA[0][j], sA[1][j]), fmaxf(sA[2][j], sA[3][j]));
                mx = fmaxf(mx, __shfl_xor(mx, 1));
                mx = fmaxf(mx, __shfl_xor(mx, 2));
                mx = fmaxf(mx, __shfl_xor(mx, 4));
                mx = fmaxf(mx, __shfl_xor(mx, 8));
                pm[j] = mx * CS;
                need = need || (pm[j] > mcs[j] + 8.0f);    // T13 defer-rescale
            }
            if (__any(need ? 1 : 0)) {
                #pragma unroll
                for (int j = 0; j < 4; ++j) {
                    float nm = fmaxf(mcs[j], pm[j]);
                    float al = exp2f(mcs[j] - nm);
                    mcs[j] = nm;
                    l[j] *= al;
                    #pragma unroll
                    for (int dt = 0; dt < 8; ++dt) o[dt][j] *= al;
                }
            }

            // ---- P = exp2(S*CS - mcs), staged per-wave (C-layout write)
            #pragma unroll
            for (int j = 0; j < 4; ++j) {
                #pragma unroll
                for (int kt = 0; kt < 4; ++kt)
                    Ps[w][lg * 4 + j][kt * 16 + lr] = f2bf(exp2f(sA[kt][j] * CS - mcs[j]));
            }
            asm volatile("s_waitcnt lgkmcnt(0)" ::: "memory");

            // ---- P A-frags; l via P*ones MFMA; PV from global Vt
            bfrag pa0 = *(const bfrag*)&Ps[w][lr][lg * 8];
            bfrag pa1 = *(const bfrag*)&Ps[w][lr][32 + lg * 8];
            f32x4 ls = mfma16(pa0, ones, mfma16(pa1, ones, z4()));
            #pragma unroll
            for (int j = 0; j < 4; ++j) l[j] += ls[j];

            #pragma unroll
            for (int dt = 0; dt < 8; ++dt) {
                const short* vp = Vb + (size_t)(dt * 16 + lr) * SEQ + k0 + lg * 8;
                bfrag vb0 = *(const bfrag*)vp;
                bfrag vb1 = *(const bfrag*)(vp + 32);
                o[dt] = mfma16(pa0, vb0, o[dt]);
                o[dt] = mfma16(pa1, vb1, o[dt]);
            }
            asm volatile("s_waitcnt lgkmcnt(0)" ::: "memory");  // pa reads done before next Ps write
        }

        // ---- epilogue: normalize, scatter bf16 into Y[8192][1024]
        #pragma unroll
        for (int j = 0; j < 4; ++j) {
            float inv = 1.0f / l[j];
            int s2 = q0 + lg * 4 + j;
            size_t yrow = (size_t)b * SEQ + n * 256 + (s2 >> 3);
            short* yp = Y + yrow * YN + (s2 & 7) * 128 + lr;
            #pragma unroll
            for (int dt = 0; dt < 8; ++dt)
                yp[dt * 16] = f2bf(o[dt][j] * inv);
        }
    }
}

// ---------------------------------------------------------------------------
// GEMM2: out[8192][128] (f32) = Yb[8192][1024](bf16) @ proj, B as projT[h][k].
// Block = 32 rows x 128 cols; 4 waves, each 32x32; grid 256.
// ---------------------------------------------------------------------------
__global__ __launch_bounds__(256) void gemm_out(
    const short* __restrict__ Yb, const short* __restrict__ projT, float* __restrict__ out)
{
    const int t = threadIdx.x, lane = t & 63, w = t >> 6;
    const int lr = lane & 15, lg = lane >> 4;
    const int m0 = blockIdx.x * 32;
    const int n0 = w * 32;

    f32x4 acc[2][2];
    #pragma unroll
    for (int i = 0; i < 2; ++i)
        #pragma unroll
        for (int j = 0; j < 2; ++j) acc[i][j] = z4();

    for (int c = 0; c < 32; ++c) {
        bfrag a[2], bb[2];
        #pragma unroll
        for (int rt = 0; rt < 2; ++rt)
            a[rt] = *(const bfrag*)(Yb + (size_t)(m0 + rt * 16 + lr) * YN + c * 32 + lg * 8);
        #pragma unroll
        for (int nt = 0; nt < 2; ++nt)
            bb[nt] = *(const bfrag*)(projT + (size_t)(n0 + nt * 16 + lr) * YN + c * 32 + lg * 8);
        #pragma unroll
        for (int rt = 0; rt < 2; ++rt)
            #pragma unroll
            for (int nt = 0; nt < 2; ++nt)
                acc[rt][nt] = mfma16(a[rt], bb[nt], acc[rt][nt]);
    }
    #pragma unroll
    for (int rt = 0; rt < 2; ++rt)
        #pragma unroll
        for (int nt = 0; nt < 2; ++nt)
            #pragma unroll
            for (int j = 0; j < 4; ++j)
                out[(size_t)(m0 + rt * 16 + lg * 4 + j) * HDIM + n0 + nt * 16 + lr] =
                    acc[rt][nt][j];
}

// ---------------------------------------------------------------------------
extern "C" void kernel_launch(void* const* d_in, const int* in_sizes, int n_in,
                              void* d_out, int out_size, void* d_ws, size_t ws_size,
                              hipStream_t stream)
{
    const float* x    = (const float*)d_in[0];  // [4,2048,128]
    const float* qkv  = (const float*)d_in[1];  // [128,3072]
    const float* proj = (const float*)d_in[2];  // [1024,128]
    float* out = (float*)d_out;                 // [8192,128]

    // Per-head buffers are [32 heads][2048 rows][128] = MROWS*YN/... = 8192*1024
    // elements each for Q/K/V/Vt (16 MB bf16), NOT MROWS*HDIM. (Round-4 bug.)
    const size_t HEADSZ = (size_t)32 * SEQ * HDIM;        // 8,388,608 elements

    short* XB    = (short*)d_ws;                          // 1,048,576 elems (2 MB)
    short* qkvT  = XB    + (size_t)MROWS * HDIM;          // 393,216
    short* projT = qkvT  + (size_t)QKVN * HDIM;           // 131,072
    short* Qh    = projT + (size_t)HDIM * YN;             // 8.4M elems (16 MB)
    short* Kh    = Qh    + HEADSZ;                        // 16 MB
    short* Vh    = Kh    + HEADSZ;                        // 16 MB
    short* Vtb   = Vh    + HEADSZ;                        // 16 MB
    short* Yb    = Vtb   + HEADSZ;                        // 16 MB  (~85 MB total)

    conv_x    <<<MROWS * HDIM / 1024, 256, 0, stream>>>(x, XB);
    conv_qkvT <<<QKVN * HDIM / 256,  256, 0, stream>>>(qkv, qkvT);
    conv_projT<<<HDIM * YN / 256,    256, 0, stream>>>(proj, projT);

    gemm_qkv<<<dim3(MROWS / 128, QKVN / 128), 256, 0, stream>>>(XB, qkvT, Qh, Kh, Vh);
    transp_v<<<dim3(SEQ / 64, HDIM / 64, 32), 256, 0, stream>>>(Vh, Vtb);
    attn2   <<<512, 256, 0, stream>>>(Qh, Kh, Vtb, Yb);
    gemm_out<<<MROWS / 32, 256, 0, stream>>>(Yb, projT, out);
}